// Round 3
// baseline (794.685 us; speedup 1.0000x reference)
//
#include <hip/hip_runtime.h>
#include <hip/hip_bf16.h>
#include <stdint.h>

#define HID 128
#define NB 16384
#define TSTEPS 28
#define BN 32

typedef __attribute__((ext_vector_type(8))) short s16x8;
typedef __attribute__((ext_vector_type(4))) float f32x4;

// LDS map: h1 [32][128]bf16 swizzled = 8KB; h0 same = 8KB; xt 2 bufs [32][32]bf16 = 2x2KB
#define H1_OFF 0
#define H0_OFF 8192
#define XT_OFF 16384
#define SMEM_BYTES 20480

__device__ __forceinline__ unsigned int f2bfu(float f) {
  union { float f; uint32_t u; } a; a.f = f;
  uint32_t r = a.u + 0x7FFFu + ((a.u >> 16) & 1u);
  return r >> 16;
}
__device__ __forceinline__ short f2bf(float f) { return (short)f2bfu(f); }
__device__ __forceinline__ unsigned int pack2bf(float lo, float hi) {
  return f2bfu(lo) | (f2bfu(hi) << 16);
}

// h tiles: 256B rows; XOR f(row)=(row^(row>>2))&7 on 16B slots.
// f is injective on {j,j+4,j+8,j+12} (gate writes) and 2-regular on 16
// consecutive rows (A-frag reads) -> both <=2 lanes/bank (free).
__device__ __forceinline__ int swzh(int row, int b) {
  return (row << 8) + (b ^ (((row ^ (row >> 2)) & 7) << 4));
}
// xt tile: 64B rows, 2-bit variant
__device__ __forceinline__ int swzx(int row, int b) {
  return (row << 6) + (b ^ (((row ^ (row >> 2)) & 3) << 4));
}

__device__ __forceinline__ float fsig(float x) {
  float e = __builtin_amdgcn_exp2f(-1.442695041f * x);
  return __builtin_amdgcn_rcpf(1.0f + e);
}
__device__ __forceinline__ float ftanh(float x) {
  float xc = fminf(fmaxf(x, -15.f), 15.f);
  float e = __builtin_amdgcn_exp2f(-2.885390082f * xc);   // e^(-2x)
  float r = __builtin_amdgcn_rcpf(1.0f + e);
  return fmaf(-2.0f * e, r, 1.0f);                        // (1-e)/(1+e)
}

__global__ __launch_bounds__(512, 4) void gru_kernel(
    const float* __restrict__ x,
    const float* __restrict__ Wih1, const float* __restrict__ Whh1,
    const float* __restrict__ bih1, const float* __restrict__ bhh1,
    const float* __restrict__ Wih2,
    const float* __restrict__ bih2, const float* __restrict__ bhh2,
    const float* __restrict__ Wout, const float* __restrict__ bout,
    float* __restrict__ out)
{
  __shared__ char smem[SMEM_BYTES];
  const int tid = threadIdx.x;
  const int wv   = tid >> 6;
  const int lane = tid & 63;
  const int l15 = lane & 15;
  const int l16 = lane >> 4;        // 0..3
  const int hc0 = wv * 16;          // this wave's hidden-column slice
  const int n0 = blockIdx.x * BN;

  // ---- preload weight B-fragments into registers (bf16) ----
  s16x8 fw_hh1[4][3], fw_ih2[4][3];
  s16x8 fw_ih1[3];
  const int gb0 = hc0, gb1 = 128 + hc0, gb2 = 256 + hc0;
  #pragma unroll
  for (int kf = 0; kf < 4; ++kf) {
    int kbase = kf * 32 + l16 * 8;
    #pragma unroll
    for (int cb = 0; cb < 3; ++cb) {
      int g = (cb == 0 ? gb0 : cb == 1 ? gb1 : gb2) + l15;
      const float* p1 = Whh1 + g * HID + kbase;
      const float* p2 = Wih2 + g * HID + kbase;
      s16x8 f1, f2;
      #pragma unroll
      for (int j = 0; j < 8; ++j) { f1[j] = f2bf(p1[j]); f2[j] = f2bf(p2[j]); }
      fw_hh1[kf][cb] = f1; fw_ih2[kf][cb] = f2;
    }
  }
  {
    int kbase = l16 * 8;
    #pragma unroll
    for (int cb = 0; cb < 3; ++cb) {
      int g = (cb == 0 ? gb0 : cb == 1 ? gb1 : gb2) + l15;
      s16x8 f;
      #pragma unroll
      for (int j = 0; j < 8; ++j) {
        int k = kbase + j;
        f[j] = (k < 28) ? f2bf(Wih1[g * 28 + k]) : (short)0;
      }
      fw_ih1[cb] = f;
    }
  }
  const float b_r  = bih1[gb0 + l15] + bhh1[gb0 + l15];
  const float b_z  = bih1[gb1 + l15] + bhh1[gb1 + l15];
  const float b_ci = bih1[gb2 + l15];
  const float b_ch = bhh1[gb2 + l15];
  const float c_r2 = bih2[gb0 + l15] + bhh2[gb0 + l15];
  const float c_z2 = bih2[gb1 + l15] + bhh2[gb1 + l15];
  const float c_c2 = bih2[gb2 + l15];
  const float c_hc2 = bhh2[gb2 + l15];   // cell2 hc = bhh2_n (h==0)

  float h1reg[2][4];
  #pragma unroll
  for (int rf = 0; rf < 2; ++rf)
    #pragma unroll
    for (int j = 0; j < 4; ++j) h1reg[rf][j] = 0.f;

  // ---- stage xt(0) into buf0 + zero h1 ----
  const int srow = tid >> 4, skp = tid & 15;
  {
    float2 v = make_float2(0.f, 0.f);
    if (skp < 14)
      v = *(const float2*)(x + (size_t)(n0 + srow) * 784 + 2 * skp);
    *(unsigned int*)(smem + XT_OFF + swzx(srow, skp * 4)) = pack2bf(v.x, v.y);
  }
  ((int4*)(smem + H1_OFF))[tid] = make_int4(0, 0, 0, 0);
  __syncthreads();

  for (int t = 0; t < TSTEPS; ++t) {
    const int xb = t & 1;
    // ---- cell 1: K = 32 (x) + 128 (h1) ----
    #pragma unroll
    for (int rf = 0; rf < 2; ++rf) {
      int arow = rf * 16 + l15;
      s16x8 ax = *(const s16x8*)(smem + XT_OFF + xb * 2048 + swzx(arow, l16 * 16));
      s16x8 ah[4];
      #pragma unroll
      for (int kf = 0; kf < 4; ++kf)
        ah[kf] = *(const s16x8*)(smem + H1_OFF + swzh(arow, kf * 64 + l16 * 16));
      f32x4 aR  = {b_r,  b_r,  b_r,  b_r };
      f32x4 aZ  = {b_z,  b_z,  b_z,  b_z };
      f32x4 aCi = {b_ci, b_ci, b_ci, b_ci};
      f32x4 aCh = {b_ch, b_ch, b_ch, b_ch};
      aR  = __builtin_amdgcn_mfma_f32_16x16x32_bf16(ax, fw_ih1[0], aR, 0, 0, 0);
      aZ  = __builtin_amdgcn_mfma_f32_16x16x32_bf16(ax, fw_ih1[1], aZ, 0, 0, 0);
      aCi = __builtin_amdgcn_mfma_f32_16x16x32_bf16(ax, fw_ih1[2], aCi, 0, 0, 0);
      #pragma unroll
      for (int kf = 0; kf < 4; ++kf) {
        aR  = __builtin_amdgcn_mfma_f32_16x16x32_bf16(ah[kf], fw_hh1[kf][0], aR, 0, 0, 0);
        aZ  = __builtin_amdgcn_mfma_f32_16x16x32_bf16(ah[kf], fw_hh1[kf][1], aZ, 0, 0, 0);
        aCh = __builtin_amdgcn_mfma_f32_16x16x32_bf16(ah[kf], fw_hh1[kf][2], aCh, 0, 0, 0);
      }
      #pragma unroll
      for (int j = 0; j < 4; ++j) {
        float r = fsig(aR[j]);
        float z = fsig(aZ[j]);
        float c = ftanh(fmaf(r, aCh[j], aCi[j]));
        float h0 = fmaxf(fmaf(z, h1reg[rf][j] - c, c), 0.f);
        int row = rf * 16 + l16 * 4 + j;
        *(short*)(smem + H0_OFF + swzh(row, (hc0 + l15) << 1)) = f2bf(h0);
      }
    }
    __syncthreads();

    // ---- cell 2 (h==0) + stage xt(t+1) into buf xb^1 ----
    float2 xv = make_float2(0.f, 0.f);
    const bool do_stage = (t + 1 < TSTEPS);
    if (do_stage && skp < 14)
      xv = *(const float2*)(x + (size_t)(n0 + srow) * 784 + (t + 1) * 28 + 2 * skp);
    #pragma unroll
    for (int rf = 0; rf < 2; ++rf) {
      int arow = rf * 16 + l15;
      s16x8 ah[4];
      #pragma unroll
      for (int kf = 0; kf < 4; ++kf)
        ah[kf] = *(const s16x8*)(smem + H0_OFF + swzh(arow, kf * 64 + l16 * 16));
      f32x4 aR = {c_r2, c_r2, c_r2, c_r2};
      f32x4 aZ = {c_z2, c_z2, c_z2, c_z2};
      f32x4 aC = {c_c2, c_c2, c_c2, c_c2};
      #pragma unroll
      for (int kf = 0; kf < 4; ++kf) {
        aR = __builtin_amdgcn_mfma_f32_16x16x32_bf16(ah[kf], fw_ih2[kf][0], aR, 0, 0, 0);
        aZ = __builtin_amdgcn_mfma_f32_16x16x32_bf16(ah[kf], fw_ih2[kf][1], aZ, 0, 0, 0);
        aC = __builtin_amdgcn_mfma_f32_16x16x32_bf16(ah[kf], fw_ih2[kf][2], aC, 0, 0, 0);
      }
      #pragma unroll
      for (int j = 0; j < 4; ++j) {
        float r2 = fsig(aR[j]);
        float z2 = fsig(aZ[j]);
        float c2 = ftanh(fmaf(r2, c_hc2, aC[j]));
        float h1n = c2 - z2 * c2;                 // (1-z2)*c2
        h1reg[rf][j] = h1n;
        int row = rf * 16 + l16 * 4 + j;
        *(short*)(smem + H1_OFF + swzh(row, (hc0 + l15) << 1)) = f2bf(h1n);
      }
    }
    if (do_stage) {
      *(unsigned int*)(smem + XT_OFF + (xb ^ 1) * 2048 + swzx(srow, skp * 4)) =
          pack2bf(xv.x, xv.y);
    }
    __syncthreads();
  }

  // ---- final projection: out = h1 @ Wout^T + bout (fp32 h1 from regs) ----
  float* houtf = (float*)smem;   // [32][132] overlay = 16896 B
  #pragma unroll
  for (int rf = 0; rf < 2; ++rf)
    #pragma unroll
    for (int j = 0; j < 4; ++j) {
      int row = rf * 16 + l16 * 4 + j;
      houtf[row * 132 + hc0 + l15] = h1reg[rf][j];
    }
  __syncthreads();
  if (tid < BN * 10) {
    int row = tid & 31;
    int o = tid >> 5;
    const float* hp = houtf + row * 132;
    const float* wp = Wout + o * HID;
    float s = bout[o];
    #pragma unroll 8
    for (int j2 = 0; j2 < HID; ++j2) s = fmaf(hp[j2], wp[j2], s);
    out[(size_t)(n0 + row) * 10 + o] = s;
  }
}

extern "C" void kernel_launch(void* const* d_in, const int* in_sizes, int n_in,
                              void* d_out, int out_size, void* d_ws, size_t ws_size,
                              hipStream_t stream) {
  const float* x    = (const float*)d_in[0];
  const float* Wih1 = (const float*)d_in[1];
  const float* Whh1 = (const float*)d_in[2];
  const float* bih1 = (const float*)d_in[3];
  const float* bhh1 = (const float*)d_in[4];
  const float* Wih2 = (const float*)d_in[5];
  // d_in[6] = Whh2: multiplied by zero hidden state in the reference -> unused
  const float* bih2 = (const float*)d_in[7];
  const float* bhh2 = (const float*)d_in[8];
  const float* Wout = (const float*)d_in[9];
  const float* bout = (const float*)d_in[10];
  gru_kernel<<<NB / BN, 512, 0, stream>>>(x, Wih1, Whh1, bih1, bhh1,
                                          Wih2, bih2, bhh2, Wout, bout,
                                          (float*)d_out);
}

// Round 4
// 184.028 us; speedup vs baseline: 4.3183x; 4.3183x over previous
//
#include <hip/hip_runtime.h>
#include <hip/hip_bf16.h>
#include <stdint.h>

#define HID 128
#define NB 16384
#define TSTEPS 28
#define BN 32

typedef __attribute__((ext_vector_type(8))) short s16x8;
typedef __attribute__((ext_vector_type(4))) float f32x4;

// LDS map: h1 [32][128]bf16 swizzled = 8KB; h0 same = 8KB; xt 2 bufs [32][32]bf16 = 2x2KB
#define H1_OFF 0
#define H0_OFF 8192
#define XT_OFF 16384
#define SMEM_BYTES 20480

__device__ __forceinline__ unsigned int f2bfu(float f) {
  union { float f; uint32_t u; } a; a.f = f;
  uint32_t r = a.u + 0x7FFFu + ((a.u >> 16) & 1u);
  return r >> 16;
}
__device__ __forceinline__ short f2bf(float f) { return (short)f2bfu(f); }
__device__ __forceinline__ unsigned int pack2bf(float lo, float hi) {
  return f2bfu(lo) | (f2bfu(hi) << 16);
}

// h tiles: 256B rows; XOR f(row)=(row^(row>>2))&7 on 16B slots.
// f is injective on {j,j+4,j+8,j+12} (gate writes) and 2-regular on 16
// consecutive rows (A-frag reads) -> both <=2 lanes/bank (free).
__device__ __forceinline__ int swzh(int row, int b) {
  return (row << 8) + (b ^ (((row ^ (row >> 2)) & 7) << 4));
}
// xt tile: 64B rows, 2-bit variant
__device__ __forceinline__ int swzx(int row, int b) {
  return (row << 6) + (b ^ (((row ^ (row >> 2)) & 3) << 4));
}

__device__ __forceinline__ float fsig(float x) {
  float e = __builtin_amdgcn_exp2f(-1.442695041f * x);
  return __builtin_amdgcn_rcpf(1.0f + e);
}
__device__ __forceinline__ float ftanh(float x) {
  float xc = fminf(fmaxf(x, -15.f), 15.f);
  float e = __builtin_amdgcn_exp2f(-2.885390082f * xc);   // e^(-2x)
  float r = __builtin_amdgcn_rcpf(1.0f + e);
  return fmaf(-2.0f * e, r, 1.0f);                        // (1-e)/(1+e)
}

// NOTE: 2nd arg = min waves per EU. (512,4) forces a 128-reg/wave budget ->
// compiler splits 64 arch + 64 acc -> 108 regs of weight frags spill to
// scratch (R3: WRITE_SIZE 380MB, 4.3x slower). Keep (512,2): 256-reg budget,
// demand ~128 -> HW can still co-schedule 2 blocks/CU if total <=128.
__global__ __launch_bounds__(512, 2) void gru_kernel(
    const float* __restrict__ x,
    const float* __restrict__ Wih1, const float* __restrict__ Whh1,
    const float* __restrict__ bih1, const float* __restrict__ bhh1,
    const float* __restrict__ Wih2,
    const float* __restrict__ bih2, const float* __restrict__ bhh2,
    const float* __restrict__ Wout, const float* __restrict__ bout,
    float* __restrict__ out)
{
  __shared__ char smem[SMEM_BYTES];
  const int tid = threadIdx.x;
  const int wv   = tid >> 6;
  const int lane = tid & 63;
  const int l15 = lane & 15;
  const int l16 = lane >> 4;        // 0..3
  const int hc0 = wv * 16;          // this wave's hidden-column slice
  const int n0 = blockIdx.x * BN;

  // ---- preload weight B-fragments into registers (bf16) ----
  s16x8 fw_hh1[4][3], fw_ih2[4][3];
  s16x8 fw_ih1[3];
  const int gb0 = hc0, gb1 = 128 + hc0, gb2 = 256 + hc0;
  #pragma unroll
  for (int kf = 0; kf < 4; ++kf) {
    int kbase = kf * 32 + l16 * 8;
    #pragma unroll
    for (int cb = 0; cb < 3; ++cb) {
      int g = (cb == 0 ? gb0 : cb == 1 ? gb1 : gb2) + l15;
      const float* p1 = Whh1 + g * HID + kbase;
      const float* p2 = Wih2 + g * HID + kbase;
      s16x8 f1, f2;
      #pragma unroll
      for (int j = 0; j < 8; ++j) { f1[j] = f2bf(p1[j]); f2[j] = f2bf(p2[j]); }
      fw_hh1[kf][cb] = f1; fw_ih2[kf][cb] = f2;
    }
  }
  {
    int kbase = l16 * 8;
    #pragma unroll
    for (int cb = 0; cb < 3; ++cb) {
      int g = (cb == 0 ? gb0 : cb == 1 ? gb1 : gb2) + l15;
      s16x8 f;
      #pragma unroll
      for (int j = 0; j < 8; ++j) {
        int k = kbase + j;
        f[j] = (k < 28) ? f2bf(Wih1[g * 28 + k]) : (short)0;
      }
      fw_ih1[cb] = f;
    }
  }
  const float b_r  = bih1[gb0 + l15] + bhh1[gb0 + l15];
  const float b_z  = bih1[gb1 + l15] + bhh1[gb1 + l15];
  const float b_ci = bih1[gb2 + l15];
  const float b_ch = bhh1[gb2 + l15];
  const float c_r2 = bih2[gb0 + l15] + bhh2[gb0 + l15];
  const float c_z2 = bih2[gb1 + l15] + bhh2[gb1 + l15];
  const float c_c2 = bih2[gb2 + l15];
  const float c_hc2 = bhh2[gb2 + l15];   // cell2 hc = bhh2_n (h==0)

  float h1reg[2][4];
  #pragma unroll
  for (int rf = 0; rf < 2; ++rf)
    #pragma unroll
    for (int j = 0; j < 4; ++j) h1reg[rf][j] = 0.f;

  // ---- stage xt(0) into buf0 + zero h1 ----
  const int srow = tid >> 4, skp = tid & 15;
  {
    float2 v = make_float2(0.f, 0.f);
    if (skp < 14)
      v = *(const float2*)(x + (size_t)(n0 + srow) * 784 + 2 * skp);
    *(unsigned int*)(smem + XT_OFF + swzx(srow, skp * 4)) = pack2bf(v.x, v.y);
  }
  ((int4*)(smem + H1_OFF))[tid] = make_int4(0, 0, 0, 0);
  __syncthreads();

  for (int t = 0; t < TSTEPS; ++t) {
    const int xb = t & 1;
    // ---- cell 1: K = 32 (x) + 128 (h1) ----
    #pragma unroll
    for (int rf = 0; rf < 2; ++rf) {
      int arow = rf * 16 + l15;
      s16x8 ax = *(const s16x8*)(smem + XT_OFF + xb * 2048 + swzx(arow, l16 * 16));
      s16x8 ah[4];
      #pragma unroll
      for (int kf = 0; kf < 4; ++kf)
        ah[kf] = *(const s16x8*)(smem + H1_OFF + swzh(arow, kf * 64 + l16 * 16));
      f32x4 aR  = {b_r,  b_r,  b_r,  b_r };
      f32x4 aZ  = {b_z,  b_z,  b_z,  b_z };
      f32x4 aCi = {b_ci, b_ci, b_ci, b_ci};
      f32x4 aCh = {b_ch, b_ch, b_ch, b_ch};
      aR  = __builtin_amdgcn_mfma_f32_16x16x32_bf16(ax, fw_ih1[0], aR, 0, 0, 0);
      aZ  = __builtin_amdgcn_mfma_f32_16x16x32_bf16(ax, fw_ih1[1], aZ, 0, 0, 0);
      aCi = __builtin_amdgcn_mfma_f32_16x16x32_bf16(ax, fw_ih1[2], aCi, 0, 0, 0);
      #pragma unroll
      for (int kf = 0; kf < 4; ++kf) {
        aR  = __builtin_amdgcn_mfma_f32_16x16x32_bf16(ah[kf], fw_hh1[kf][0], aR, 0, 0, 0);
        aZ  = __builtin_amdgcn_mfma_f32_16x16x32_bf16(ah[kf], fw_hh1[kf][1], aZ, 0, 0, 0);
        aCh = __builtin_amdgcn_mfma_f32_16x16x32_bf16(ah[kf], fw_hh1[kf][2], aCh, 0, 0, 0);
      }
      #pragma unroll
      for (int j = 0; j < 4; ++j) {
        float r = fsig(aR[j]);
        float z = fsig(aZ[j]);
        float c = ftanh(fmaf(r, aCh[j], aCi[j]));
        float h0 = fmaxf(fmaf(z, h1reg[rf][j] - c, c), 0.f);
        int row = rf * 16 + l16 * 4 + j;
        *(short*)(smem + H0_OFF + swzh(row, (hc0 + l15) << 1)) = f2bf(h0);
      }
    }
    __syncthreads();

    // ---- cell 2 (h==0) + stage xt(t+1) into buf xb^1 ----
    float2 xv = make_float2(0.f, 0.f);
    const bool do_stage = (t + 1 < TSTEPS);
    if (do_stage && skp < 14)
      xv = *(const float2*)(x + (size_t)(n0 + srow) * 784 + (t + 1) * 28 + 2 * skp);
    #pragma unroll
    for (int rf = 0; rf < 2; ++rf) {
      int arow = rf * 16 + l15;
      s16x8 ah[4];
      #pragma unroll
      for (int kf = 0; kf < 4; ++kf)
        ah[kf] = *(const s16x8*)(smem + H0_OFF + swzh(arow, kf * 64 + l16 * 16));
      f32x4 aR = {c_r2, c_r2, c_r2, c_r2};
      f32x4 aZ = {c_z2, c_z2, c_z2, c_z2};
      f32x4 aC = {c_c2, c_c2, c_c2, c_c2};
      #pragma unroll
      for (int kf = 0; kf < 4; ++kf) {
        aR = __builtin_amdgcn_mfma_f32_16x16x32_bf16(ah[kf], fw_ih2[kf][0], aR, 0, 0, 0);
        aZ = __builtin_amdgcn_mfma_f32_16x16x32_bf16(ah[kf], fw_ih2[kf][1], aZ, 0, 0, 0);
        aC = __builtin_amdgcn_mfma_f32_16x16x32_bf16(ah[kf], fw_ih2[kf][2], aC, 0, 0, 0);
      }
      #pragma unroll
      for (int j = 0; j < 4; ++j) {
        float r2 = fsig(aR[j]);
        float z2 = fsig(aZ[j]);
        float c2 = ftanh(fmaf(r2, c_hc2, aC[j]));
        float h1n = c2 - z2 * c2;                 // (1-z2)*c2
        h1reg[rf][j] = h1n;
        int row = rf * 16 + l16 * 4 + j;
        *(short*)(smem + H1_OFF + swzh(row, (hc0 + l15) << 1)) = f2bf(h1n);
      }
    }
    if (do_stage) {
      *(unsigned int*)(smem + XT_OFF + (xb ^ 1) * 2048 + swzx(srow, skp * 4)) =
          pack2bf(xv.x, xv.y);
    }
    __syncthreads();
  }

  // ---- final projection: out = h1 @ Wout^T + bout (fp32 h1 from regs) ----
  float* houtf = (float*)smem;   // [32][132] overlay = 16896 B
  #pragma unroll
  for (int rf = 0; rf < 2; ++rf)
    #pragma unroll
    for (int j = 0; j < 4; ++j) {
      int row = rf * 16 + l16 * 4 + j;
      houtf[row * 132 + hc0 + l15] = h1reg[rf][j];
    }
  __syncthreads();
  if (tid < BN * 10) {
    int row = tid & 31;
    int o = tid >> 5;
    const float* hp = houtf + row * 132;
    const float* wp = Wout + o * HID;
    float s = bout[o];
    #pragma unroll 8
    for (int j2 = 0; j2 < HID; ++j2) s = fmaf(hp[j2], wp[j2], s);
    out[(size_t)(n0 + row) * 10 + o] = s;
  }
}

extern "C" void kernel_launch(void* const* d_in, const int* in_sizes, int n_in,
                              void* d_out, int out_size, void* d_ws, size_t ws_size,
                              hipStream_t stream) {
  const float* x    = (const float*)d_in[0];
  const float* Wih1 = (const float*)d_in[1];
  const float* Whh1 = (const float*)d_in[2];
  const float* bih1 = (const float*)d_in[3];
  const float* bhh1 = (const float*)d_in[4];
  const float* Wih2 = (const float*)d_in[5];
  // d_in[6] = Whh2: multiplied by zero hidden state in the reference -> unused
  const float* bih2 = (const float*)d_in[7];
  const float* bhh2 = (const float*)d_in[8];
  const float* Wout = (const float*)d_in[9];
  const float* bout = (const float*)d_in[10];
  gru_kernel<<<NB / BN, 512, 0, stream>>>(x, Wih1, Whh1, bih1, bhh1,
                                          Wih2, bih2, bhh2, Wout, bout,
                                          (float*)d_out);
}

// Round 5
// 176.012 us; speedup vs baseline: 4.5150x; 1.0455x over previous
//
#include <hip/hip_runtime.h>
#include <hip/hip_bf16.h>
#include <stdint.h>

#define HID 128
#define NB 16384
#define TSTEPS 28
#define BN 32

typedef __attribute__((ext_vector_type(8))) short s16x8;
typedef __attribute__((ext_vector_type(4))) float f32x4;

// LDS map: h1 [32][128]bf16 swizzled = 8KB; h0 same = 8KB; xt 2 bufs [32][32]bf16 = 2x2KB
#define H1_OFF 0
#define H0_OFF 8192
#define XT_OFF 16384
#define SMEM_BYTES 20480

__device__ __forceinline__ unsigned int f2bfu(float f) {
  union { float f; uint32_t u; } a; a.f = f;
  uint32_t r = a.u + 0x7FFFu + ((a.u >> 16) & 1u);
  return r >> 16;
}
__device__ __forceinline__ short f2bf(float f) { return (short)f2bfu(f); }
__device__ __forceinline__ unsigned int pack2bf(float lo, float hi) {
  return f2bfu(lo) | (f2bfu(hi) << 16);
}

// h tiles: 256B rows; XOR f(row)=(row^(row>>2))&7 on 16B slots.
__device__ __forceinline__ int swzh(int row, int b) {
  return (row << 8) + (b ^ (((row ^ (row >> 2)) & 7) << 4));
}
// xt tile: 64B rows, 2-bit variant
__device__ __forceinline__ int swzx(int row, int b) {
  return (row << 6) + (b ^ (((row ^ (row >> 2)) & 3) << 4));
}

__device__ __forceinline__ float fsig(float x) {
  float e = __builtin_amdgcn_exp2f(-1.442695041f * x);
  return __builtin_amdgcn_rcpf(1.0f + e);
}
__device__ __forceinline__ float ftanh(float x) {
  float xc = fminf(fmaxf(x, -15.f), 15.f);
  float e = __builtin_amdgcn_exp2f(-2.885390082f * xc);   // e^(-2x)
  float r = __builtin_amdgcn_rcpf(1.0f + e);
  return fmaf(-2.0f * e, r, 1.0f);                        // (1-e)/(1+e)
}

// Register-budget ledger (R3/R4 post-mortems):
//   unified pool = 512 regs/EU; budget = 512 / min_waves_arg.
//   (512,4): 128 total -> 64 arch: catastrophic spill (380MB scratch writes).
//   (512,2): 256 total -> compiler pins 128 arch + 128 acc; arch demand ~170
//            -> ~44 dwords/thread spilled (45.7MB WRITE_SIZE, R4).
//   (512,1): 512 total -> arch cap 256 >= demand -> no spill; residency is
//            8 waves/CU either way (weights-in-regs design needs ~170 arch).
__global__ __launch_bounds__(512, 1) void gru_kernel(
    const float* __restrict__ x,
    const float* __restrict__ Wih1, const float* __restrict__ Whh1,
    const float* __restrict__ bih1, const float* __restrict__ bhh1,
    const float* __restrict__ Wih2,
    const float* __restrict__ bih2, const float* __restrict__ bhh2,
    const float* __restrict__ Wout, const float* __restrict__ bout,
    float* __restrict__ out)
{
  __shared__ char smem[SMEM_BYTES];
  const int tid = threadIdx.x;
  const int wv   = tid >> 6;
  const int lane = tid & 63;
  const int l15 = lane & 15;
  const int l16 = lane >> 4;        // 0..3
  const int hc0 = wv * 16;          // this wave's hidden-column slice
  const int n0 = blockIdx.x * BN;

  // ---- preload weight B-fragments into registers (bf16) ----
  s16x8 fw_hh1[4][3], fw_ih2[4][3];
  s16x8 fw_ih1[3];
  const int gb0 = hc0, gb1 = 128 + hc0, gb2 = 256 + hc0;
  #pragma unroll
  for (int kf = 0; kf < 4; ++kf) {
    int kbase = kf * 32 + l16 * 8;
    #pragma unroll
    for (int cb = 0; cb < 3; ++cb) {
      int g = (cb == 0 ? gb0 : cb == 1 ? gb1 : gb2) + l15;
      const float* p1 = Whh1 + g * HID + kbase;
      const float* p2 = Wih2 + g * HID + kbase;
      s16x8 f1, f2;
      #pragma unroll
      for (int j = 0; j < 8; ++j) { f1[j] = f2bf(p1[j]); f2[j] = f2bf(p2[j]); }
      fw_hh1[kf][cb] = f1; fw_ih2[kf][cb] = f2;
    }
  }
  {
    int kbase = l16 * 8;
    #pragma unroll
    for (int cb = 0; cb < 3; ++cb) {
      int g = (cb == 0 ? gb0 : cb == 1 ? gb1 : gb2) + l15;
      s16x8 f;
      #pragma unroll
      for (int j = 0; j < 8; ++j) {
        int k = kbase + j;
        f[j] = (k < 28) ? f2bf(Wih1[g * 28 + k]) : (short)0;
      }
      fw_ih1[cb] = f;
    }
  }
  const float b_r  = bih1[gb0 + l15] + bhh1[gb0 + l15];
  const float b_z  = bih1[gb1 + l15] + bhh1[gb1 + l15];
  const float b_ci = bih1[gb2 + l15];
  const float b_ch = bhh1[gb2 + l15];
  const float c_r2 = bih2[gb0 + l15] + bhh2[gb0 + l15];
  const float c_z2 = bih2[gb1 + l15] + bhh2[gb1 + l15];
  const float c_c2 = bih2[gb2 + l15];
  const float c_hc2 = bhh2[gb2 + l15];   // cell2 hc = bhh2_n (h==0)

  float h1reg[2][4];
  #pragma unroll
  for (int rf = 0; rf < 2; ++rf)
    #pragma unroll
    for (int j = 0; j < 4; ++j) h1reg[rf][j] = 0.f;

  // ---- stage xt(0) into buf0 + zero h1 ----
  const int srow = tid >> 4, skp = tid & 15;
  {
    float2 v = make_float2(0.f, 0.f);
    if (skp < 14)
      v = *(const float2*)(x + (size_t)(n0 + srow) * 784 + 2 * skp);
    *(unsigned int*)(smem + XT_OFF + swzx(srow, skp * 4)) = pack2bf(v.x, v.y);
  }
  ((int4*)(smem + H1_OFF))[tid] = make_int4(0, 0, 0, 0);
  __syncthreads();

  // unroll 1: cross-step software pipelining can't cross the barriers anyway,
  // but full unroll inflates peak register pressure (R4 spill evidence).
  #pragma unroll 1
  for (int t = 0; t < TSTEPS; ++t) {
    const int xb = t & 1;
    // ---- cell 1: K = 32 (x) + 128 (h1) ----
    #pragma unroll
    for (int rf = 0; rf < 2; ++rf) {
      int arow = rf * 16 + l15;
      s16x8 ax = *(const s16x8*)(smem + XT_OFF + xb * 2048 + swzx(arow, l16 * 16));
      s16x8 ah[4];
      #pragma unroll
      for (int kf = 0; kf < 4; ++kf)
        ah[kf] = *(const s16x8*)(smem + H1_OFF + swzh(arow, kf * 64 + l16 * 16));
      f32x4 aR  = {b_r,  b_r,  b_r,  b_r };
      f32x4 aZ  = {b_z,  b_z,  b_z,  b_z };
      f32x4 aCi = {b_ci, b_ci, b_ci, b_ci};
      f32x4 aCh = {b_ch, b_ch, b_ch, b_ch};
      aR  = __builtin_amdgcn_mfma_f32_16x16x32_bf16(ax, fw_ih1[0], aR, 0, 0, 0);
      aZ  = __builtin_amdgcn_mfma_f32_16x16x32_bf16(ax, fw_ih1[1], aZ, 0, 0, 0);
      aCi = __builtin_amdgcn_mfma_f32_16x16x32_bf16(ax, fw_ih1[2], aCi, 0, 0, 0);
      #pragma unroll
      for (int kf = 0; kf < 4; ++kf) {
        aR  = __builtin_amdgcn_mfma_f32_16x16x32_bf16(ah[kf], fw_hh1[kf][0], aR, 0, 0, 0);
        aZ  = __builtin_amdgcn_mfma_f32_16x16x32_bf16(ah[kf], fw_hh1[kf][1], aZ, 0, 0, 0);
        aCh = __builtin_amdgcn_mfma_f32_16x16x32_bf16(ah[kf], fw_hh1[kf][2], aCh, 0, 0, 0);
      }
      #pragma unroll
      for (int j = 0; j < 4; ++j) {
        float r = fsig(aR[j]);
        float z = fsig(aZ[j]);
        float c = ftanh(fmaf(r, aCh[j], aCi[j]));
        float h0 = fmaxf(fmaf(z, h1reg[rf][j] - c, c), 0.f);
        int row = rf * 16 + l16 * 4 + j;
        *(short*)(smem + H0_OFF + swzh(row, (hc0 + l15) << 1)) = f2bf(h0);
      }
    }
    __syncthreads();

    // ---- cell 2 (h==0) + stage xt(t+1) into buf xb^1 ----
    float2 xv = make_float2(0.f, 0.f);
    const bool do_stage = (t + 1 < TSTEPS);
    if (do_stage && skp < 14)
      xv = *(const float2*)(x + (size_t)(n0 + srow) * 784 + (t + 1) * 28 + 2 * skp);
    #pragma unroll
    for (int rf = 0; rf < 2; ++rf) {
      int arow = rf * 16 + l15;
      s16x8 ah[4];
      #pragma unroll
      for (int kf = 0; kf < 4; ++kf)
        ah[kf] = *(const s16x8*)(smem + H0_OFF + swzh(arow, kf * 64 + l16 * 16));
      f32x4 aR = {c_r2, c_r2, c_r2, c_r2};
      f32x4 aZ = {c_z2, c_z2, c_z2, c_z2};
      f32x4 aC = {c_c2, c_c2, c_c2, c_c2};
      #pragma unroll
      for (int kf = 0; kf < 4; ++kf) {
        aR = __builtin_amdgcn_mfma_f32_16x16x32_bf16(ah[kf], fw_ih2[kf][0], aR, 0, 0, 0);
        aZ = __builtin_amdgcn_mfma_f32_16x16x32_bf16(ah[kf], fw_ih2[kf][1], aZ, 0, 0, 0);
        aC = __builtin_amdgcn_mfma_f32_16x16x32_bf16(ah[kf], fw_ih2[kf][2], aC, 0, 0, 0);
      }
      #pragma unroll
      for (int j = 0; j < 4; ++j) {
        float r2 = fsig(aR[j]);
        float z2 = fsig(aZ[j]);
        float c2 = ftanh(fmaf(r2, c_hc2, aC[j]));
        float h1n = c2 - z2 * c2;                 // (1-z2)*c2
        h1reg[rf][j] = h1n;
        int row = rf * 16 + l16 * 4 + j;
        *(short*)(smem + H1_OFF + swzh(row, (hc0 + l15) << 1)) = f2bf(h1n);
      }
    }
    if (do_stage) {
      *(unsigned int*)(smem + XT_OFF + (xb ^ 1) * 2048 + swzx(srow, skp * 4)) =
          pack2bf(xv.x, xv.y);
    }
    __syncthreads();
  }

  // ---- final projection: out = h1 @ Wout^T + bout (fp32 h1 from regs) ----
  float* houtf = (float*)smem;   // [32][132] overlay = 16896 B
  #pragma unroll
  for (int rf = 0; rf < 2; ++rf)
    #pragma unroll
    for (int j = 0; j < 4; ++j) {
      int row = rf * 16 + l16 * 4 + j;
      houtf[row * 132 + hc0 + l15] = h1reg[rf][j];
    }
  __syncthreads();
  if (tid < BN * 10) {
    int row = tid & 31;
    int o = tid >> 5;
    const float* hp = houtf + row * 132;
    const float* wp = Wout + o * HID;
    float s = bout[o];
    #pragma unroll 8
    for (int j2 = 0; j2 < HID; ++j2) s = fmaf(hp[j2], wp[j2], s);
    out[(size_t)(n0 + row) * 10 + o] = s;
  }
}

extern "C" void kernel_launch(void* const* d_in, const int* in_sizes, int n_in,
                              void* d_out, int out_size, void* d_ws, size_t ws_size,
                              hipStream_t stream) {
  const float* x    = (const float*)d_in[0];
  const float* Wih1 = (const float*)d_in[1];
  const float* Whh1 = (const float*)d_in[2];
  const float* bih1 = (const float*)d_in[3];
  const float* bhh1 = (const float*)d_in[4];
  const float* Wih2 = (const float*)d_in[5];
  // d_in[6] = Whh2: multiplied by zero hidden state in the reference -> unused
  const float* bih2 = (const float*)d_in[7];
  const float* bhh2 = (const float*)d_in[8];
  const float* Wout = (const float*)d_in[9];
  const float* bout = (const float*)d_in[10];
  gru_kernel<<<NB / BN, 512, 0, stream>>>(x, Wih1, Whh1, bih1, bhh1,
                                          Wih2, bih2, bhh2, Wout, bout,
                                          (float*)d_out);
}